// Round 9
// baseline (356.717 us; speedup 1.0000x reference)
//
#include <hip/hip_runtime.h>

// ---------------- problem constants ----------------
#define D_MODEL 1024
#define HID     2752
#define NEXP    8
#define NTOK    4096
#define ALPHA   0.05f

typedef __bf16 bf16_t;
typedef bf16_t bf16x8 __attribute__((ext_vector_type(8)));
typedef float  f32x4  __attribute__((ext_vector_type(4)));

__device__ inline unsigned short f2bf(float f) {
    unsigned int u = __float_as_uint(f);
    u += 0x7fffu + ((u >> 16) & 1u);   // round-to-nearest-even
    return (unsigned short)(u >> 16);
}

__device__ inline bf16x8 ldsFrag(const unsigned short* p) {
    union { uint4 u; bf16x8 b; } t;
    t.u = *(const uint4*)p;
    return t.b;
}

__device__ inline void gload_lds16(const void* g, void* l) {
    __builtin_amdgcn_global_load_lds((const __attribute__((address_space(1))) void*)g,
                                     (__attribute__((address_space(3))) void*)l, 16, 0, 0);
}

// ---------------- combined weight transpose+convert ----------------
// z in [0,24): z<8 -> Wu[e], z<16 -> Wv[e-8], z>=16 -> Wd[e-16].
// Wu/Wv: [D_MODEL][HID] f32 -> [HID][D_MODEL] bf16 (r0=y*64 over D_MODEL, c0=x*64 over HID)
// Wd:    [HID][D_MODEL] f32 -> [D_MODEL][HID] bf16 (r0=x*64 over HID, c0=y*64 over D_MODEL)
__global__ __launch_bounds__(256) void transposeAll_kernel(const float* __restrict__ Wu,
                                                           const float* __restrict__ Wv,
                                                           const float* __restrict__ Wd,
                                                           unsigned short* __restrict__ WuT,
                                                           unsigned short* __restrict__ WvT,
                                                           unsigned short* __restrict__ WdT) {
    __shared__ float tile[64 * 65];
    const int z = blockIdx.z;
    const int tid = threadIdx.x;
    const float* src;
    unsigned short* dst;
    int R, C, r0, c0;
    if (z < 16) {
        const int e = z & 7;
        src = ((z < 8) ? Wu : Wv) + (size_t)e * D_MODEL * HID;
        dst = ((z < 8) ? WuT : WvT) + (size_t)e * D_MODEL * HID;
        R = D_MODEL; C = HID;
        r0 = blockIdx.y * 64; c0 = blockIdx.x * 64;
    } else {
        const int e = z - 16;
        src = Wd + (size_t)e * HID * D_MODEL;
        dst = WdT + (size_t)e * HID * D_MODEL;
        R = HID; C = D_MODEL;
        r0 = blockIdx.x * 64; c0 = blockIdx.y * 64;
    }
#pragma unroll
    for (int j = 0; j < 4; ++j) {
        int f = j * 256 + tid;
        int row = f >> 4, c4 = f & 15;
        float4 v = *(const float4*)(src + (size_t)(r0 + row) * C + c0 + c4 * 4);
        float* t = &tile[row * 65 + c4 * 4];
        t[0] = v.x; t[1] = v.y; t[2] = v.z; t[3] = v.w;
    }
    __syncthreads();
#pragma unroll
    for (int j = 0; j < 2; ++j) {
        int f = j * 256 + tid;
        int orow = f >> 3, kc = f & 7;
        unsigned short pk[8];
#pragma unroll
        for (int q = 0; q < 8; ++q) pk[q] = f2bf(tile[(kc * 8 + q) * 65 + orow]);
        *(uint4*)(dst + (size_t)(c0 + orow) * R + r0 + kc * 8) = *(uint4*)pk;
    }
}

// standalone Wd transpose (fallback when WdT must alias WuT)
__global__ __launch_bounds__(256) void transpose_kernel(const float* __restrict__ in,
                                                        unsigned short* __restrict__ out,
                                                        int R, int C) {
    __shared__ float tile[64 * 65];
    const int e = blockIdx.z;
    const float* src = in + (size_t)e * R * C;
    unsigned short* dst = out + (size_t)e * R * C;
    const int c0 = blockIdx.x * 64, r0 = blockIdx.y * 64;
    const int tid = threadIdx.x;
#pragma unroll
    for (int j = 0; j < 4; ++j) {
        int f = j * 256 + tid;
        int row = f >> 4, c4 = f & 15;
        float4 v = *(const float4*)(src + (size_t)(r0 + row) * C + c0 + c4 * 4);
        float* t = &tile[row * 65 + c4 * 4];
        t[0] = v.x; t[1] = v.y; t[2] = v.z; t[3] = v.w;
    }
    __syncthreads();
#pragma unroll
    for (int j = 0; j < 2; ++j) {
        int f = j * 256 + tid;
        int orow = f >> 3, kc = f & 7;
        unsigned short pk[8];
#pragma unroll
        for (int q = 0; q < 8; ++q) pk[q] = f2bf(tile[(kc * 8 + q) * 65 + orow]);
        *(uint4*)(dst + (size_t)(c0 + orow) * R + r0 + kc * 8) = *(uint4*)pk;
    }
}

// ---------------- router (fused x->bf16 conversion) ----------------
__global__ void router_kernel(const float* __restrict__ x, const float* __restrict__ Wg,
                              const float* __restrict__ bg,
                              int* __restrict__ eidx, float* __restrict__ gate_p,
                              int* __restrict__ counts, float* __restrict__ ce_sum,
                              unsigned short* __restrict__ xbf) {
    __shared__ float ceS[8];
    __shared__ int   cntS[8];
    int tid = threadIdx.x;
    if (tid < 8) { ceS[tid] = 0.f; cntS[tid] = 0; }
    __syncthreads();

    int wid = tid >> 6, lane = tid & 63;
    int t = blockIdx.x * 16 + wid;
    const float* xr = x + (size_t)t * D_MODEL;
    unsigned short* xbr = xbf + (size_t)t * D_MODEL;

    float acc[8];
#pragma unroll
    for (int e = 0; e < 8; ++e) acc[e] = 0.f;

#pragma unroll
    for (int c = 0; c < 4; ++c) {
        int i0 = c * 256 + lane * 4;
        float4 xv = *(const float4*)(xr + i0);
        uint2 pk;
        pk.x = (unsigned)f2bf(xv.x) | ((unsigned)f2bf(xv.y) << 16);
        pk.y = (unsigned)f2bf(xv.z) | ((unsigned)f2bf(xv.w) << 16);
        *(uint2*)(xbr + i0) = pk;
#pragma unroll
        for (int j = 0; j < 4; ++j) {
            const float* wr = Wg + (size_t)(i0 + j) * 8;
            float4 lo = *(const float4*)(wr);
            float4 hi = *(const float4*)(wr + 4);
            float xs = (&xv.x)[j];
            acc[0] += xs * lo.x; acc[1] += xs * lo.y;
            acc[2] += xs * lo.z; acc[3] += xs * lo.w;
            acc[4] += xs * hi.x; acc[5] += xs * hi.y;
            acc[6] += xs * hi.z; acc[7] += xs * hi.w;
        }
    }
#pragma unroll
    for (int e = 0; e < 8; ++e) {
#pragma unroll
        for (int off = 32; off > 0; off >>= 1)
            acc[e] += __shfl_xor(acc[e], off, 64);
    }

    if (lane == 0) {
        float lg[8];
#pragma unroll
        for (int e = 0; e < 8; ++e) lg[e] = acc[e] + bg[e];
        float mx = lg[0]; int am = 0;
#pragma unroll
        for (int e = 1; e < 8; ++e) { if (lg[e] > mx) { mx = lg[e]; am = e; } }
        float ex[8], s = 0.f;
#pragma unroll
        for (int e = 0; e < 8; ++e) { ex[e] = __expf(lg[e] - mx); s += ex[e]; }
        float inv = 1.f / s;
#pragma unroll
        for (int e = 0; e < 8; ++e) atomicAdd(&ceS[e], ex[e] * inv);
        atomicAdd(&cntS[am], 1);
        eidx[t] = am;
        gate_p[t] = ex[am] * inv;
    }
    __syncthreads();
    if (tid < 8) atomicAdd(&ce_sum[tid], ceS[tid]);
    if (tid >= 8 && tid < 16) atomicAdd(&counts[tid - 8], cntS[tid - 8]);
}

// ---------------- offsets + aux loss ----------------
__global__ void offsets_aux_kernel(const int* __restrict__ counts, const float* __restrict__ ce_sum,
                                   int* __restrict__ offs, float* __restrict__ aux_out) {
    if (threadIdx.x == 0) {
        int off = 0; float aux = 0.f;
        for (int e = 0; e < 8; ++e) {
            offs[e] = off; off += counts[e];
            aux += ((float)counts[e] / (float)NTOK) * (ce_sum[e] / (float)NTOK);
        }
        aux_out[0] = ALPHA * (float)NEXP * aux;
    }
}

// ---------------- scatter ----------------
__global__ void scatter_kernel(const int* __restrict__ eidx, const int* __restrict__ offs,
                               int* __restrict__ fill, int* __restrict__ toks) {
    int t = blockIdx.x * 256 + threadIdx.x;
    int e = eidx[t];
    int pos = atomicAdd(&fill[e], 1);
    toks[offs[e] + pos] = t;
}

// ======================= GEMM1 =======================
// h = silu(X WuT^T) * (X WvT^T). 128m x 64n tile, BK=64, 4 waves (64x32 each),
// single-buffer 2-barrier body (round-2 proven), 32KB LDS -> 4 blocks/CU at
// launch_bounds(256,4) (VGPR cap 128; round-6 measured 96 for this shape).
// Grid dim3(43, 32, 8) nt-fastest (round-2/5 proven ordering; no XCD pin).
__global__ __launch_bounds__(256, 4) void gemm1_kernel(
    const unsigned short* __restrict__ WuT, const unsigned short* __restrict__ WvT,
    const unsigned short* __restrict__ xbf,
    const int* __restrict__ toks, const int* __restrict__ counts, const int* __restrict__ offs,
    unsigned short* __restrict__ hbuf) {
    const int e  = blockIdx.z;
    const int mt = blockIdx.y;
    const int nt = blockIdx.x;           // 0..42
    const int Ne = counts[e];
    if (mt * 128 >= Ne) return;
    const int slot0 = offs[e] + mt * 128;
    const int rowsV = min(128, Ne - mt * 128);
    const int ncol0 = nt * 64;

    __shared__ unsigned short As[128 * 64];   // 16 KB
    __shared__ unsigned short Bus[64 * 64];   //  8 KB
    __shared__ unsigned short Bvs[64 * 64];   //  8 KB

    const int tid = threadIdx.x;

    const unsigned short* aS[4];
    unsigned short* aD[4];
#pragma unroll
    for (int i = 0; i < 4; ++i) {
        int c = i * 256 + tid;
        int r = c >> 3, ch = c & 7;
        int srcOff = (ch ^ (r & 7)) * 8;
        int ar = min(r, rowsV - 1);
        int tok = toks[slot0 + ar];
        aS[i] = xbf + (size_t)tok * D_MODEL + srcOff;
        aD[i] = As + c * 8;
    }
    const unsigned short *buS[2], *bvS[2];
    unsigned short *buD[2], *bvD[2];
#pragma unroll
    for (int i = 0; i < 2; ++i) {
        int c = i * 256 + tid;
        int r = c >> 3, ch = c & 7;
        int srcOff = (ch ^ (r & 7)) * 8;
        int bn = ncol0 + r;
        buS[i] = WuT + ((size_t)e * HID + bn) * D_MODEL + srcOff;
        bvS[i] = WvT + ((size_t)e * HID + bn) * D_MODEL + srcOff;
        buD[i] = Bus + c * 8;
        bvD[i] = Bvs + c * 8;
    }

    f32x4 accU[4][2], accV[4][2];
#pragma unroll
    for (int m = 0; m < 4; ++m)
#pragma unroll
        for (int n = 0; n < 2; ++n) {
            accU[m][n] = (f32x4){0.f, 0.f, 0.f, 0.f};
            accV[m][n] = (f32x4){0.f, 0.f, 0.f, 0.f};
        }

    const int lane = tid & 63;
    const int w = tid >> 6;
    const int rbase = (w >> 1) * 64;
    const int cbase = (w & 1) * 32;
    const int lrow = lane & 15;
    const int lchunk = lane >> 4;

    for (int ks = 0; ks < 16; ++ks) {
#pragma unroll
        for (int i = 0; i < 4; ++i) { gload_lds16(aS[i], aD[i]); aS[i] += 64; }
#pragma unroll
        for (int i = 0; i < 2; ++i) {
            gload_lds16(buS[i], buD[i]); buS[i] += 64;
            gload_lds16(bvS[i], bvD[i]); bvS[i] += 64;
        }
        __syncthreads();

#pragma unroll
        for (int kk = 0; kk < 2; ++kk) {
            const int g = kk * 4 + lchunk;
            bf16x8 af[4], bu[2], bv[2];
#pragma unroll
            for (int m = 0; m < 4; ++m) {
                int r = rbase + m * 16 + lrow;
                af[m] = ldsFrag(&As[r * 64 + ((g ^ (r & 7)) * 8)]);
            }
#pragma unroll
            for (int n = 0; n < 2; ++n) {
                int rn = cbase + n * 16 + lrow;
                int off = rn * 64 + ((g ^ (rn & 7)) * 8);
                bu[n] = ldsFrag(&Bus[off]);
                bv[n] = ldsFrag(&Bvs[off]);
            }
#pragma unroll
            for (int m = 0; m < 4; ++m)
#pragma unroll
                for (int n = 0; n < 2; ++n) {
                    accU[m][n] = __builtin_amdgcn_mfma_f32_16x16x32_bf16(af[m], bu[n], accU[m][n], 0, 0, 0);
                    accV[m][n] = __builtin_amdgcn_mfma_f32_16x16x32_bf16(af[m], bv[n], accV[m][n], 0, 0, 0);
                }
        }
        __syncthreads();
    }

    // epilogue: h = silu(u) * v (bf16); HID = 43*64 so no column guard
#pragma unroll
    for (int m = 0; m < 4; ++m) {
#pragma unroll
        for (int i = 0; i < 4; ++i) {
            int r = rbase + m * 16 + (lane >> 4) * 4 + i;
            if (r >= rowsV) continue;
            size_t rowOff = (size_t)(slot0 + r) * HID + ncol0;
#pragma unroll
            for (int n = 0; n < 2; ++n) {
                int c = cbase + n * 16 + (lane & 15);
                float u = accU[m][n][i];
                float v = accV[m][n][i];
                float s = u / (1.f + __expf(-u));
                hbuf[rowOff + c] = f2bf(s * v);
            }
        }
    }
}

// ======================= GEMM2 =======================
// y[tok] = p * (h WdT^T). 128m x 64n, BK=64, static ping-pong dbuf (48KB LDS).
// XCD-pinned 1D grid: id = e + 8*(mt + 32*nt). (Proven rounds 6-8; untouched.)

#define G2_STAGE(AS, BS)                                                  \
    {                                                                     \
        _Pragma("unroll")                                                 \
        for (int i = 0; i < 4; ++i) { gload_lds16(aS[i], &AS[aOff[i]]); aS[i] += 64; } \
        _Pragma("unroll")                                                 \
        for (int i = 0; i < 2; ++i) { gload_lds16(bS[i], &BS[bOff[i]]); bS[i] += 64; } \
    }

#define G2_COMPUTE(AS, BS)                                                \
    {                                                                     \
        _Pragma("unroll")                                                 \
        for (int kk = 0; kk < 2; ++kk) {                                  \
            const int g = kk * 4 + lchunk;                                \
            bf16x8 af[4], bf[2];                                          \
            _Pragma("unroll")                                             \
            for (int m = 0; m < 4; ++m) {                                 \
                int r = rbase + m * 16 + lrow;                            \
                af[m] = ldsFrag(&AS[r * 64 + ((g ^ (r & 7)) * 8)]);       \
            }                                                             \
            _Pragma("unroll")                                             \
            for (int n = 0; n < 2; ++n) {                                 \
                int rn = cbase + n * 16 + lrow;                           \
                bf[n] = ldsFrag(&BS[rn * 64 + ((g ^ (rn & 7)) * 8)]);     \
            }                                                             \
            __builtin_amdgcn_s_setprio(1);                                \
            _Pragma("unroll")                                             \
            for (int m = 0; m < 4; ++m)                                   \
                _Pragma("unroll")                                         \
                for (int n = 0; n < 2; ++n)                               \
                    acc[m][n] = __builtin_amdgcn_mfma_f32_16x16x32_bf16(af[m], bf[n], acc[m][n], 0, 0, 0); \
            __builtin_amdgcn_s_setprio(0);                                \
        }                                                                 \
    }

__global__ __launch_bounds__(256, 2) void gemm2_kernel(
    const unsigned short* __restrict__ WdT, const unsigned short* __restrict__ hbuf,
    const int* __restrict__ toks, const int* __restrict__ counts, const int* __restrict__ offs,
    const float* __restrict__ gate_p, float* __restrict__ yout) {
    const int id = blockIdx.x;
    const int e  = id & 7;
    const int j  = id >> 3;
    const int mt = j & 31;
    const int nt = j >> 5;          // 0..15
    const int Ne = counts[e];
    if (mt * 128 >= Ne) return;
    const int slot0 = offs[e] + mt * 128;
    const int rowsV = min(128, Ne - mt * 128);
    const int ncol0 = nt * 64;

    __shared__ unsigned short As0[128 * 64];
    __shared__ unsigned short As1[128 * 64];
    __shared__ unsigned short Bs0[64 * 64];
    __shared__ unsigned short Bs1[64 * 64];

    const int tid = threadIdx.x;

    const unsigned short* aS[4];
    int aOff[4];
#pragma unroll
    for (int i = 0; i < 4; ++i) {
        int c = i * 256 + tid;
        int r = c >> 3, ch = c & 7;
        int srcOff = (ch ^ (r & 7)) * 8;
        int ar = min(r, rowsV - 1);
        aS[i] = hbuf + (size_t)(slot0 + ar) * HID + srcOff;
        aOff[i] = c * 8;
    }
    const unsigned short* bS[2];
    int bOff[2];
#pragma unroll
    for (int i = 0; i < 2; ++i) {
        int c = i * 256 + tid;
        int r = c >> 3, ch = c & 7;
        int srcOff = (ch ^ (r & 7)) * 8;
        bS[i] = WdT + ((size_t)e * D_MODEL + ncol0 + r) * HID + srcOff;
        bOff[i] = c * 8;
    }

    f32x4 acc[4][2];
#pragma unroll
    for (int m = 0; m < 4; ++m)
#pragma unroll
        for (int n = 0; n < 2; ++n) acc[m][n] = (f32x4){0.f, 0.f, 0.f, 0.f};

    const int lane = tid & 63;
    const int w = tid >> 6;
    const int rbase = (w >> 1) * 64;
    const int cbase = (w & 1) * 32;
    const int lrow = lane & 15;
    const int lchunk = lane >> 4;

    // prologue: step 0 -> buf0
    G2_STAGE(As0, Bs0);
    __syncthreads();

    // 43 K-steps: 21 ping-pong pairs (steps 0..41) + epilogue step 42 in buf0
#pragma unroll 1
    for (int k2 = 0; k2 < 21; ++k2) {
        G2_STAGE(As1, Bs1);          // step 2k+1
        G2_COMPUTE(As0, Bs0);        // step 2k
        __syncthreads();
        G2_STAGE(As0, Bs0);          // step 2k+2  (<= 42)
        G2_COMPUTE(As1, Bs1);        // step 2k+1
        __syncthreads();
    }
    G2_COMPUTE(As0, Bs0);            // step 42

#pragma unroll
    for (int m = 0; m < 4; ++m) {
#pragma unroll
        for (int i = 0; i < 4; ++i) {
            int r = rbase + m * 16 + (lane >> 4) * 4 + i;
            if (r >= rowsV) continue;
            int tok = toks[slot0 + r];
            float p = gate_p[tok];
            float* yrow = yout + (size_t)tok * D_MODEL + ncol0;
#pragma unroll
            for (int n = 0; n < 2; ++n) {
                int c = cbase + n * 16 + (lane & 15);
                yrow[c] = p * acc[m][n][i];
            }
        }
    }
}

// ---------------- launch ----------------
extern "C" void kernel_launch(void* const* d_in, const int* in_sizes, int n_in,
                              void* d_out, int out_size, void* d_ws, size_t ws_size,
                              hipStream_t stream) {
    const float* x  = (const float*)d_in[0];
    const float* Wg = (const float*)d_in[1];
    const float* bg = (const float*)d_in[2];
    const float* Wu = (const float*)d_in[3];
    const float* Wv = (const float*)d_in[4];
    const float* Wd = (const float*)d_in[5];
    float* yout = (float*)d_out;
    float* aux_out = yout + (size_t)NTOK * D_MODEL;

    char* ws = (char*)d_ws;
    int*   counts = (int*)(ws + 0);
    int*   offs   = (int*)(ws + 32);
    float* ce_sum = (float*)(ws + 64);
    int*   fill   = (int*)(ws + 96);
    int*   eidx   = (int*)(ws + 128);
    float* gate_p = (float*)(ws + 16512);
    int*   toks   = (int*)(ws + 32896);
    unsigned short* xbf  = (unsigned short*)(ws + 65536);      // 8 MB
    unsigned short* hbuf = (unsigned short*)(ws + 8454144);    // 22.5 MB
    unsigned short* WuT  = (unsigned short*)(ws + 30998528);   // 43 MB
    unsigned short* WvT  = (unsigned short*)(ws + 76087296);   // 43 MB
    const size_t WDT_OFF = 121176064;
    const size_t WDT_SZ  = (size_t)NEXP * D_MODEL * HID * 2;   // 43 MB
    const bool sepWdT = ws_size >= WDT_OFF + WDT_SZ;           // proven true (round 7)
    unsigned short* WdT = sepWdT ? (unsigned short*)(ws + WDT_OFF) : WuT;

    hipMemsetAsync(ws, 0, 128, stream);
    router_kernel<<<256, 1024, 0, stream>>>(x, Wg, bg, eidx, gate_p, counts, ce_sum, xbf);
    offsets_aux_kernel<<<1, 64, 0, stream>>>(counts, ce_sum, offs, aux_out);
    scatter_kernel<<<16, 256, 0, stream>>>(eidx, offs, fill, toks);
    transposeAll_kernel<<<dim3(HID / 64, D_MODEL / 64, sepWdT ? 24 : 16), 256, 0, stream>>>(
        Wu, Wv, Wd, WuT, WvT, WdT);
    gemm1_kernel<<<dim3(43, 32, 8), 256, 0, stream>>>(WuT, WvT, xbf, toks, counts, offs, hbuf);
    if (!sepWdT)
        transpose_kernel<<<dim3(D_MODEL / 64, HID / 64, 8), 256, 0, stream>>>(Wd, WdT, HID, D_MODEL);
    gemm2_kernel<<<8 * 32 * 16, 256, 0, stream>>>(WdT, hbuf, toks, counts, offs, gate_p, yout);
}

// Round 10
// 258.257 us; speedup vs baseline: 1.3812x; 1.3812x over previous
//
#include <hip/hip_runtime.h>

// ---------------- problem constants ----------------
#define D_MODEL 1024
#define HID     2752
#define NEXP    8
#define NTOK    4096
#define ALPHA   0.05f

// prep kernel block counts
#define TILES_UV  (43 * 16 * 16)   // 11008: Wu+Wv transpose tiles
#define TILES_WD  (16 * 43 * 8)    // 5504 : Wd transpose tiles
#define RTR_BLKS  1024             // router role: 4 tokens per 256-thr block

typedef __bf16 bf16_t;
typedef bf16_t bf16x8 __attribute__((ext_vector_type(8)));
typedef float  f32x4  __attribute__((ext_vector_type(4)));

__device__ inline unsigned short f2bf(float f) {
    unsigned int u = __float_as_uint(f);
    u += 0x7fffu + ((u >> 16) & 1u);   // round-to-nearest-even
    return (unsigned short)(u >> 16);
}

__device__ inline bf16x8 ldsFrag(const unsigned short* p) {
    union { uint4 u; bf16x8 b; } t;
    t.u = *(const uint4*)p;
    return t.b;
}

__device__ inline void gload_lds16(const void* g, void* l) {
    __builtin_amdgcn_global_load_lds((const __attribute__((address_space(1))) void*)g,
                                     (__attribute__((address_space(3))) void*)l, 16, 0, 0);
}

// ---------------- prep: weight transposes + router, one dispatch ----------------
// id < nTiles: transpose role. z = id/688, (bx,by) in 43x16.
//   z<8: Wu[e=z], z<16: Wv[e=z-8]  ([D_MODEL][HID] f32 -> [HID][D_MODEL] bf16)
//   z>=16 (only when sepWdT): Wd[e=z-16] ([HID][D_MODEL] f32 -> [D_MODEL][HID] bf16)
// id >= nTiles: router role, 4 tokens per block (1/wave), fused x->bf16.
__global__ __launch_bounds__(256) void prep_kernel(
    const float* __restrict__ x, const float* __restrict__ Wg, const float* __restrict__ bg,
    const float* __restrict__ Wu, const float* __restrict__ Wv, const float* __restrict__ Wd,
    unsigned short* __restrict__ WuT, unsigned short* __restrict__ WvT,
    unsigned short* __restrict__ WdT,
    int* __restrict__ eidx, float* __restrict__ gate_p,
    int* __restrict__ counts, float* __restrict__ ce_sum,
    unsigned short* __restrict__ xbf, int nTiles) {

    __shared__ float smem[64 * 65];
    const int id = blockIdx.x;
    const int tid = threadIdx.x;

    if (id < nTiles) {
        // ---- transpose role ----
        const int z  = id / 688;
        const int rm = id - z * 688;
        const int bx = rm % 43;
        const int by = rm / 43;
        const float* src;
        unsigned short* dst;
        int R, C, r0, c0;
        if (z < 16) {
            const int e = z & 7;
            src = ((z < 8) ? Wu : Wv) + (size_t)e * D_MODEL * HID;
            dst = ((z < 8) ? WuT : WvT) + (size_t)e * D_MODEL * HID;
            R = D_MODEL; C = HID;
            r0 = by * 64; c0 = bx * 64;
        } else {
            const int e = z - 16;
            src = Wd + (size_t)e * HID * D_MODEL;
            dst = WdT + (size_t)e * HID * D_MODEL;
            R = HID; C = D_MODEL;
            r0 = bx * 64; c0 = by * 64;
        }
#pragma unroll
        for (int j = 0; j < 4; ++j) {
            int f = j * 256 + tid;
            int row = f >> 4, c4 = f & 15;
            float4 v = *(const float4*)(src + (size_t)(r0 + row) * C + c0 + c4 * 4);
            float* t = &smem[row * 65 + c4 * 4];
            t[0] = v.x; t[1] = v.y; t[2] = v.z; t[3] = v.w;
        }
        __syncthreads();
#pragma unroll
        for (int j = 0; j < 2; ++j) {
            int f = j * 256 + tid;
            int orow = f >> 3, kc = f & 7;
            unsigned short pk[8];
#pragma unroll
            for (int q = 0; q < 8; ++q) pk[q] = f2bf(smem[(kc * 8 + q) * 65 + orow]);
            *(uint4*)(dst + (size_t)(c0 + orow) * R + r0 + kc * 8) = *(uint4*)pk;
        }
        return;
    }

    // ---- router role ----
    float* ceS = smem;            // 8 floats
    int*   cntS = (int*)(smem + 8);
    if (tid < 8) { ceS[tid] = 0.f; cntS[tid] = 0; }
    __syncthreads();

    const int rid = id - nTiles;
    const int wid = tid >> 6, lane = tid & 63;
    const int t = rid * 4 + wid;
    const float* xr = x + (size_t)t * D_MODEL;
    unsigned short* xbr = xbf + (size_t)t * D_MODEL;

    float acc[8];
#pragma unroll
    for (int e = 0; e < 8; ++e) acc[e] = 0.f;

#pragma unroll
    for (int c = 0; c < 4; ++c) {
        int i0 = c * 256 + lane * 4;
        float4 xv = *(const float4*)(xr + i0);
        uint2 pk;
        pk.x = (unsigned)f2bf(xv.x) | ((unsigned)f2bf(xv.y) << 16);
        pk.y = (unsigned)f2bf(xv.z) | ((unsigned)f2bf(xv.w) << 16);
        *(uint2*)(xbr + i0) = pk;
#pragma unroll
        for (int j = 0; j < 4; ++j) {
            const float* wr = Wg + (size_t)(i0 + j) * 8;
            float4 lo = *(const float4*)(wr);
            float4 hi = *(const float4*)(wr + 4);
            float xs = (&xv.x)[j];
            acc[0] += xs * lo.x; acc[1] += xs * lo.y;
            acc[2] += xs * lo.z; acc[3] += xs * lo.w;
            acc[4] += xs * hi.x; acc[5] += xs * hi.y;
            acc[6] += xs * hi.z; acc[7] += xs * hi.w;
        }
    }
#pragma unroll
    for (int e = 0; e < 8; ++e) {
#pragma unroll
        for (int off = 32; off > 0; off >>= 1)
            acc[e] += __shfl_xor(acc[e], off, 64);
    }

    if (lane == 0) {
        float lg[8];
#pragma unroll
        for (int e = 0; e < 8; ++e) lg[e] = acc[e] + bg[e];
        float mx = lg[0]; int am = 0;
#pragma unroll
        for (int e = 1; e < 8; ++e) { if (lg[e] > mx) { mx = lg[e]; am = e; } }
        float ex[8], s = 0.f;
#pragma unroll
        for (int e = 0; e < 8; ++e) { ex[e] = __expf(lg[e] - mx); s += ex[e]; }
        float inv = 1.f / s;
#pragma unroll
        for (int e = 0; e < 8; ++e) atomicAdd(&ceS[e], ex[e] * inv);
        atomicAdd(&cntS[am], 1);
        eidx[t] = am;
        gate_p[t] = ex[am] * inv;
    }
    __syncthreads();
    if (tid < 8) atomicAdd(&ce_sum[tid], ceS[tid]);
    if (tid >= 8 && tid < 16) atomicAdd(&counts[tid - 8], cntS[tid - 8]);
}

// standalone Wd transpose (fallback when WdT must alias WuT; runs after gemm1)
__global__ __launch_bounds__(256) void transpose_kernel(const float* __restrict__ in,
                                                        unsigned short* __restrict__ out,
                                                        int R, int C) {
    __shared__ float tile[64 * 65];
    const int e = blockIdx.z;
    const float* src = in + (size_t)e * R * C;
    unsigned short* dst = out + (size_t)e * R * C;
    const int c0 = blockIdx.x * 64, r0 = blockIdx.y * 64;
    const int tid = threadIdx.x;
#pragma unroll
    for (int j = 0; j < 4; ++j) {
        int f = j * 256 + tid;
        int row = f >> 4, c4 = f & 15;
        float4 v = *(const float4*)(src + (size_t)(r0 + row) * C + c0 + c4 * 4);
        float* t = &tile[row * 65 + c4 * 4];
        t[0] = v.x; t[1] = v.y; t[2] = v.z; t[3] = v.w;
    }
    __syncthreads();
#pragma unroll
    for (int j = 0; j < 2; ++j) {
        int f = j * 256 + tid;
        int orow = f >> 3, kc = f & 7;
        unsigned short pk[8];
#pragma unroll
        for (int q = 0; q < 8; ++q) pk[q] = f2bf(tile[(kc * 8 + q) * 65 + orow]);
        *(uint4*)(dst + (size_t)(c0 + orow) * R + r0 + kc * 8) = *(uint4*)pk;
    }
}

// ---------------- offsets + aux loss ----------------
__global__ void offsets_aux_kernel(const int* __restrict__ counts, const float* __restrict__ ce_sum,
                                   int* __restrict__ offs, float* __restrict__ aux_out) {
    if (threadIdx.x == 0) {
        int off = 0; float aux = 0.f;
        for (int e = 0; e < 8; ++e) {
            offs[e] = off; off += counts[e];
            aux += ((float)counts[e] / (float)NTOK) * (ce_sum[e] / (float)NTOK);
        }
        aux_out[0] = ALPHA * (float)NEXP * aux;
    }
}

// ---------------- scatter ----------------
__global__ void scatter_kernel(const int* __restrict__ eidx, const int* __restrict__ offs,
                               int* __restrict__ fill, int* __restrict__ toks) {
    int t = blockIdx.x * 256 + threadIdx.x;
    int e = eidx[t];
    int pos = atomicAdd(&fill[e], 1);
    toks[offs[e] + pos] = t;
}

// ======================= GEMM1 =======================
// h = silu(X WuT^T) * (X WvT^T). Round-2 proven body verbatim: 128x128 tile,
// BK=64, 4 waves, single-buffer 2-barrier, launch_bounds(256,2), VGPR 108,
// grid dim3(22, 32, 8) nt-fastest. Measured 101-107 us across rounds 2/5.
__global__ __launch_bounds__(256, 2) void gemm1_kernel(
    const unsigned short* __restrict__ WuT, const unsigned short* __restrict__ WvT,
    const unsigned short* __restrict__ xbf,
    const int* __restrict__ toks, const int* __restrict__ counts, const int* __restrict__ offs,
    unsigned short* __restrict__ hbuf) {
    const int e = blockIdx.z;
    const int Ne = counts[e];
    const int mt = blockIdx.y;
    if (mt * 128 >= Ne) return;
    const int nt = blockIdx.x;
    const int slot0 = offs[e] + mt * 128;
    const int rowsV = min(128, Ne - mt * 128);
    const int ncol0 = nt * 128;
    const int colsV = min(128, HID - ncol0);

    __shared__ unsigned short As[128 * 64];
    __shared__ unsigned short Bus[128 * 64];
    __shared__ unsigned short Bvs[128 * 64];

    const int tid = threadIdx.x;

    const unsigned short* aS[4];
    const unsigned short* buS[4];
    const unsigned short* bvS[4];
    unsigned short* aD[4];
    unsigned short* buD[4];
    unsigned short* bvD[4];
#pragma unroll
    for (int i = 0; i < 4; ++i) {
        int c = i * 256 + tid;
        int r = c >> 3, ch = c & 7;
        int srcOff = ((ch ^ (r & 7)) * 8);
        int ar = min(r, rowsV - 1);
        int tok = toks[slot0 + ar];
        aS[i] = xbf + (size_t)tok * D_MODEL + srcOff;
        int bn = ncol0 + min(r, colsV - 1);
        buS[i] = WuT + ((size_t)e * HID + bn) * D_MODEL + srcOff;
        bvS[i] = WvT + ((size_t)e * HID + bn) * D_MODEL + srcOff;
        aD[i]  = As  + c * 8;
        buD[i] = Bus + c * 8;
        bvD[i] = Bvs + c * 8;
    }

    f32x4 accU[4][4], accV[4][4];
#pragma unroll
    for (int m = 0; m < 4; ++m)
#pragma unroll
        for (int n = 0; n < 4; ++n) {
            accU[m][n] = (f32x4){0.f, 0.f, 0.f, 0.f};
            accV[m][n] = (f32x4){0.f, 0.f, 0.f, 0.f};
        }

    const int lane = tid & 63;
    const int w = tid >> 6;
    const int rbase = (w >> 1) * 64;
    const int cbase = (w & 1) * 64;
    const int lrow = lane & 15;
    const int lchunk = lane >> 4;

    for (int ks = 0; ks < 16; ++ks) {
#pragma unroll
        for (int i = 0; i < 4; ++i) gload_lds16(aS[i],  aD[i]);
#pragma unroll
        for (int i = 0; i < 4; ++i) gload_lds16(buS[i], buD[i]);
#pragma unroll
        for (int i = 0; i < 4; ++i) gload_lds16(bvS[i], bvD[i]);
#pragma unroll
        for (int i = 0; i < 4; ++i) { aS[i] += 64; buS[i] += 64; bvS[i] += 64; }
        __syncthreads();

#pragma unroll
        for (int kk = 0; kk < 2; ++kk) {
            const int g = kk * 4 + lchunk;
            bf16x8 af[4], bu[4], bv[4];
#pragma unroll
            for (int m = 0; m < 4; ++m) {
                int r = rbase + m * 16 + lrow;
                af[m] = ldsFrag(&As[r * 64 + ((g ^ (r & 7)) * 8)]);
            }
#pragma unroll
            for (int n = 0; n < 4; ++n) {
                int rn = cbase + n * 16 + lrow;
                int off = rn * 64 + ((g ^ (rn & 7)) * 8);
                bu[n] = ldsFrag(&Bus[off]);
                bv[n] = ldsFrag(&Bvs[off]);
            }
#pragma unroll
            for (int m = 0; m < 4; ++m)
#pragma unroll
                for (int n = 0; n < 4; ++n) {
                    accU[m][n] = __builtin_amdgcn_mfma_f32_16x16x32_bf16(af[m], bu[n], accU[m][n], 0, 0, 0);
                    accV[m][n] = __builtin_amdgcn_mfma_f32_16x16x32_bf16(af[m], bv[n], accV[m][n], 0, 0, 0);
                }
        }
        __syncthreads();
    }

    // epilogue: h = silu(u) * v (bf16)
#pragma unroll
    for (int m = 0; m < 4; ++m) {
#pragma unroll
        for (int i = 0; i < 4; ++i) {
            int r = rbase + m * 16 + (lane >> 4) * 4 + i;
            if (r >= rowsV) continue;
            size_t rowOff = (size_t)(slot0 + r) * HID + ncol0;
#pragma unroll
            for (int n = 0; n < 4; ++n) {
                int c = cbase + n * 16 + (lane & 15);
                if (c < colsV) {
                    float u = accU[m][n][i];
                    float v = accV[m][n][i];
                    float s = u / (1.f + __expf(-u));
                    hbuf[rowOff + c] = f2bf(s * v);
                }
            }
        }
    }
}

// ======================= GEMM2 =======================
// y[tok] = p * (h WdT^T). 128m x 64n, BK=64, static ping-pong dbuf (48KB LDS).
// XCD-pinned 1D grid: id = e + 8*(mt + 32*nt). (Proven rounds 6-9; untouched.)

#define G2_STAGE(AS, BS)                                                  \
    {                                                                     \
        _Pragma("unroll")                                                 \
        for (int i = 0; i < 4; ++i) { gload_lds16(aS[i], &AS[aOff[i]]); aS[i] += 64; } \
        _Pragma("unroll")                                                 \
        for (int i = 0; i < 2; ++i) { gload_lds16(bS[i], &BS[bOff[i]]); bS[i] += 64; } \
    }

#define G2_COMPUTE(AS, BS)                                                \
    {                                                                     \
        _Pragma("unroll")                                                 \
        for (int kk = 0; kk < 2; ++kk) {                                  \
            const int g = kk * 4 + lchunk;                                \
            bf16x8 af[4], bf[2];                                          \
            _Pragma("unroll")                                             \
            for (int m = 0; m < 4; ++m) {                                 \
                int r = rbase + m * 16 + lrow;                            \
                af[m] = ldsFrag(&AS[r * 64 + ((g ^ (r & 7)) * 8)]);       \
            }                                                             \
            _Pragma("unroll")                                             \
            for (int n = 0; n < 2; ++n) {                                 \
                int rn = cbase + n * 16 + lrow;                           \
                bf[n] = ldsFrag(&BS[rn * 64 + ((g ^ (rn & 7)) * 8)]);     \
            }                                                             \
            __builtin_amdgcn_s_setprio(1);                                \
            _Pragma("unroll")                                             \
            for (int m = 0; m < 4; ++m)                                   \
                _Pragma("unroll")                                         \
                for (int n = 0; n < 2; ++n)                               \
                    acc[m][n] = __builtin_amdgcn_mfma_f32_16x16x32_bf16(af[m], bf[n], acc[m][n], 0, 0, 0); \
            __builtin_amdgcn_s_setprio(0);                                \
        }                                                                 \
    }

__global__ __launch_bounds__(256, 2) void gemm2_kernel(
    const unsigned short* __restrict__ WdT, const unsigned short* __restrict__ hbuf,
    const int* __restrict__ toks, const int* __restrict__ counts, const int* __restrict__ offs,
    const float* __restrict__ gate_p, float* __restrict__ yout) {
    const int id = blockIdx.x;
    const int e  = id & 7;
    const int j  = id >> 3;
    const int mt = j & 31;
    const int nt = j >> 5;          // 0..15
    const int Ne = counts[e];
    if (mt * 128 >= Ne) return;
    const int slot0 = offs[e] + mt * 128;
    const int rowsV = min(128, Ne - mt * 128);
    const int ncol0 = nt * 64;

    __shared__ unsigned short As0[128 * 64];
    __shared__ unsigned short As1[128 * 64];
    __shared__ unsigned short Bs0[64 * 64];
    __shared__ unsigned short Bs1[64 * 64];

    const int tid = threadIdx.x;

    const unsigned short* aS[4];
    int aOff[4];
#pragma unroll
    for (int i = 0; i < 4; ++i) {
        int c = i * 256 + tid;
        int r = c >> 3, ch = c & 7;
        int srcOff = (ch ^ (r & 7)) * 8;
        int ar = min(r, rowsV - 1);
        aS[i] = hbuf + (size_t)(slot0 + ar) * HID + srcOff;
        aOff[i] = c * 8;
    }
    const unsigned short* bS[2];
    int bOff[2];
#pragma unroll
    for (int i = 0; i < 2; ++i) {
        int c = i * 256 + tid;
        int r = c >> 3, ch = c & 7;
        int srcOff = (ch ^ (r & 7)) * 8;
        bS[i] = WdT + ((size_t)e * D_MODEL + ncol0 + r) * HID + srcOff;
        bOff[i] = c * 8;
    }

    f32x4 acc[4][2];
#pragma unroll
    for (int m = 0; m < 4; ++m)
#pragma unroll
        for (int n = 0; n < 2; ++n) acc[m][n] = (f32x4){0.f, 0.f, 0.f, 0.f};

    const int lane = tid & 63;
    const int w = tid >> 6;
    const int rbase = (w >> 1) * 64;
    const int cbase = (w & 1) * 32;
    const int lrow = lane & 15;
    const int lchunk = lane >> 4;

    // prologue: step 0 -> buf0
    G2_STAGE(As0, Bs0);
    __syncthreads();

    // 43 K-steps: 21 ping-pong pairs (steps 0..41) + epilogue step 42 in buf0
#pragma unroll 1
    for (int k2 = 0; k2 < 21; ++k2) {
        G2_STAGE(As1, Bs1);          // step 2k+1
        G2_COMPUTE(As0, Bs0);        // step 2k
        __syncthreads();
        G2_STAGE(As0, Bs0);          // step 2k+2  (<= 42)
        G2_COMPUTE(As1, Bs1);        // step 2k+1
        __syncthreads();
    }
    G2_COMPUTE(As0, Bs0);            // step 42

#pragma unroll
    for (int m = 0; m < 4; ++m) {
#pragma unroll
        for (int i = 0; i < 4; ++i) {
            int r = rbase + m * 16 + (lane >> 4) * 4 + i;
            if (r >= rowsV) continue;
            int tok = toks[slot0 + r];
            float p = gate_p[tok];
            float* yrow = yout + (size_t)tok * D_MODEL + ncol0;
#pragma unroll
            for (int n = 0; n < 2; ++n) {
                int c = cbase + n * 16 + (lane & 15);
                yrow[c] = p * acc[m][n][i];
            }
        }
    }
}

// ---------------- launch ----------------
extern "C" void kernel_launch(void* const* d_in, const int* in_sizes, int n_in,
                              void* d_out, int out_size, void* d_ws, size_t ws_size,
                              hipStream_t stream) {
    const float* x  = (const float*)d_in[0];
    const float* Wg = (const float*)d_in[1];
    const float* bg = (const float*)d_in[2];
    const float* Wu = (const float*)d_in[3];
    const float* Wv = (const float*)d_in[4];
    const float* Wd = (const float*)d_in[5];
    float* yout = (float*)d_out;
    float* aux_out = yout + (size_t)NTOK * D_MODEL;

    char* ws = (char*)d_ws;
    int*   counts = (int*)(ws + 0);
    int*   offs   = (int*)(ws + 32);
    float* ce_sum = (float*)(ws + 64);
    int*   fill   = (int*)(ws + 96);
    int*   eidx   = (int*)(ws + 128);
    float* gate_p = (float*)(ws + 16512);
    int*   toks   = (int*)(ws + 32896);
    unsigned short* xbf  = (unsigned short*)(ws + 65536);      // 8 MB
    unsigned short* hbuf = (unsigned short*)(ws + 8454144);    // 22.5 MB
    unsigned short* WuT  = (unsigned short*)(ws + 30998528);   // 43 MB
    unsigned short* WvT  = (unsigned short*)(ws + 76087296);   // 43 MB
    const size_t WDT_OFF = 121176064;
    const size_t WDT_SZ  = (size_t)NEXP * D_MODEL * HID * 2;   // 43 MB
    const bool sepWdT = ws_size >= WDT_OFF + WDT_SZ;           // proven true (round 7)
    unsigned short* WdT = sepWdT ? (unsigned short*)(ws + WDT_OFF) : WuT;

    const int nTiles = sepWdT ? (TILES_UV + TILES_WD) : TILES_UV;

    hipMemsetAsync(ws, 0, 128, stream);
    prep_kernel<<<nTiles + RTR_BLKS, 256, 0, stream>>>(
        x, Wg, bg, Wu, Wv, Wd, WuT, WvT, WdT,
        eidx, gate_p, counts, ce_sum, xbf, nTiles);
    offsets_aux_kernel<<<1, 64, 0, stream>>>(counts, ce_sum, offs, aux_out);
    scatter_kernel<<<16, 256, 0, stream>>>(eidx, offs, fill, toks);
    gemm1_kernel<<<dim3(22, 32, 8), 256, 0, stream>>>(WuT, WvT, xbf, toks, counts, offs, hbuf);
    if (!sepWdT)
        transpose_kernel<<<dim3(D_MODEL / 64, HID / 64, 8), 256, 0, stream>>>(Wd, WdT, HID, D_MODEL);
    gemm2_kernel<<<8 * 32 * 16, 256, 0, stream>>>(WdT, hbuf, toks, counts, offs, gate_p, yout);
}

// Round 12
// 251.956 us; speedup vs baseline: 1.4158x; 1.0250x over previous
//
#include <hip/hip_runtime.h>

// ---------------- problem constants ----------------
#define D_MODEL 1024
#define HID     2752
#define NEXP    8
#define NTOK    4096
#define ALPHA   0.05f

// prep kernel block counts
#define TILES_UV  (43 * 16 * 16)   // 11008: Wu+Wv transpose tiles
#define TILES_WD  (16 * 43 * 8)    // 5504 : Wd transpose tiles
#define RTR_BLKS  1024             // router role: 4 tokens per 256-thr block

// bf16 transpose tile stride (elements): 66 -> phase-1 b32 writes 2-way, phase-2 u16 reads <=4-way
#define TS 66

typedef __bf16 bf16_t;
typedef bf16_t bf16x8 __attribute__((ext_vector_type(8)));
typedef float  f32x4  __attribute__((ext_vector_type(4)));
typedef float  vf4    __attribute__((ext_vector_type(4)));   // native vec for nontemporal builtins

__device__ inline unsigned short f2bf(float f) {
    unsigned int u = __float_as_uint(f);
    u += 0x7fffu + ((u >> 16) & 1u);   // round-to-nearest-even
    return (unsigned short)(u >> 16);
}

__device__ inline bf16x8 ldsFrag(const unsigned short* p) {
    union { uint4 u; bf16x8 b; } t;
    t.u = *(const uint4*)p;
    return t.b;
}

__device__ inline void gload_lds16(const void* g, void* l) {
    __builtin_amdgcn_global_load_lds((const __attribute__((address_space(1))) void*)g,
                                     (__attribute__((address_space(3))) void*)l, 16, 0, 0);
}

// ---------------- prep: weight transposes + router, one dispatch ----------------
// id < nTiles: transpose role (bf16 LDS tile, convert-in-phase-1).
// id >= nTiles: router role, 4 tokens per block, fused x->bf16.
__global__ __launch_bounds__(256) void prep_kernel(
    const float* __restrict__ x, const float* __restrict__ Wg, const float* __restrict__ bg,
    const float* __restrict__ Wu, const float* __restrict__ Wv, const float* __restrict__ Wd,
    unsigned short* __restrict__ WuT, unsigned short* __restrict__ WvT,
    unsigned short* __restrict__ WdT,
    int* __restrict__ eidx, float* __restrict__ gate_p,
    int* __restrict__ counts, float* __restrict__ ce_sum,
    unsigned short* __restrict__ xbf, int nTiles) {

    __shared__ __align__(16) unsigned short tile[64 * TS];   // 8448 B
    const int id = blockIdx.x;
    const int tid = threadIdx.x;

    if (id < nTiles) {
        // ---- transpose role: [R][C] f32 -> [C][R] bf16, 64x64 tile ----
        const int z  = id / 688;
        const int rm = id - z * 688;
        const int bx = rm % 43;
        const int by = rm / 43;
        const float* src;
        unsigned short* dst;
        int R, C, r0, c0;
        if (z < 16) {
            const int e = z & 7;
            src = ((z < 8) ? Wu : Wv) + (size_t)e * D_MODEL * HID;
            dst = ((z < 8) ? WuT : WvT) + (size_t)e * D_MODEL * HID;
            R = D_MODEL; C = HID;
            r0 = by * 64; c0 = bx * 64;
        } else {
            const int e = z - 16;
            src = Wd + (size_t)e * HID * D_MODEL;
            dst = WdT + (size_t)e * HID * D_MODEL;
            R = HID; C = D_MODEL;
            r0 = bx * 64; c0 = by * 64;
        }
        // phase 1: load f32 rows (nontemporal), convert to bf16 in regs, write pairs to LDS
#pragma unroll
        for (int j = 0; j < 4; ++j) {
            int f = j * 256 + tid;
            int row = f >> 4, c4 = (f & 15) * 4;
            vf4 v = __builtin_nontemporal_load(
                (const vf4*)(src + (size_t)(r0 + row) * C + c0 + c4));
            unsigned int p0 = (unsigned)f2bf(v.x) | ((unsigned)f2bf(v.y) << 16);
            unsigned int p1 = (unsigned)f2bf(v.z) | ((unsigned)f2bf(v.w) << 16);
            unsigned int* tp = (unsigned int*)&tile[row * TS + c4];
            tp[0] = p0; tp[1] = p1;
        }
        __syncthreads();
        // phase 2: gather 8 column elements (u16), pack, 16B store
#pragma unroll
        for (int j = 0; j < 2; ++j) {
            int f = j * 256 + tid;
            int oc = f >> 3, kc = f & 7;       // oc = source col = dst row
            unsigned int w[4];
#pragma unroll
            for (int q = 0; q < 4; ++q) {
                unsigned int lo = tile[(kc * 8 + 2 * q)     * TS + oc];
                unsigned int hi = tile[(kc * 8 + 2 * q + 1) * TS + oc];
                w[q] = lo | (hi << 16);
            }
            uint4 out; out.x = w[0]; out.y = w[1]; out.z = w[2]; out.w = w[3];
            *(uint4*)(dst + (size_t)(c0 + oc) * R + r0 + kc * 8) = out;
        }
        return;
    }

    // ---- router role ----
    float* ceS = (float*)tile;            // 8 floats
    int*   cntS = (int*)tile + 8;
    if (tid < 8) { ceS[tid] = 0.f; cntS[tid] = 0; }
    __syncthreads();

    const int rid = id - nTiles;
    const int wid = tid >> 6, lane = tid & 63;
    const int t = rid * 4 + wid;
    const float* xr = x + (size_t)t * D_MODEL;
    unsigned short* xbr = xbf + (size_t)t * D_MODEL;

    float acc[8];
#pragma unroll
    for (int e = 0; e < 8; ++e) acc[e] = 0.f;

#pragma unroll
    for (int c = 0; c < 4; ++c) {
        int i0 = c * 256 + lane * 4;
        float4 xv = *(const float4*)(xr + i0);
        uint2 pk;
        pk.x = (unsigned)f2bf(xv.x) | ((unsigned)f2bf(xv.y) << 16);
        pk.y = (unsigned)f2bf(xv.z) | ((unsigned)f2bf(xv.w) << 16);
        *(uint2*)(xbr + i0) = pk;
#pragma unroll
        for (int j = 0; j < 4; ++j) {
            const float* wr = Wg + (size_t)(i0 + j) * 8;
            float4 lo = *(const float4*)(wr);
            float4 hi = *(const float4*)(wr + 4);
            float xs = (&xv.x)[j];
            acc[0] += xs * lo.x; acc[1] += xs * lo.y;
            acc[2] += xs * lo.z; acc[3] += xs * lo.w;
            acc[4] += xs * hi.x; acc[5] += xs * hi.y;
            acc[6] += xs * hi.z; acc[7] += xs * hi.w;
        }
    }
#pragma unroll
    for (int e = 0; e < 8; ++e) {
#pragma unroll
        for (int off = 32; off > 0; off >>= 1)
            acc[e] += __shfl_xor(acc[e], off, 64);
    }

    if (lane == 0) {
        float lg[8];
#pragma unroll
        for (int e = 0; e < 8; ++e) lg[e] = acc[e] + bg[e];
        float mx = lg[0]; int am = 0;
#pragma unroll
        for (int e = 1; e < 8; ++e) { if (lg[e] > mx) { mx = lg[e]; am = e; } }
        float ex[8], s = 0.f;
#pragma unroll
        for (int e = 0; e < 8; ++e) { ex[e] = __expf(lg[e] - mx); s += ex[e]; }
        float inv = 1.f / s;
#pragma unroll
        for (int e = 0; e < 8; ++e) atomicAdd(&ceS[e], ex[e] * inv);
        atomicAdd(&cntS[am], 1);
        eidx[t] = am;
        gate_p[t] = ex[am] * inv;
    }
    __syncthreads();
    if (tid < 8) atomicAdd(&ce_sum[tid], ceS[tid]);
    if (tid >= 8 && tid < 16) atomicAdd(&counts[tid - 8], cntS[tid - 8]);
}

// standalone Wd transpose (fallback when WdT must alias WuT; runs after gemm1)
__global__ __launch_bounds__(256) void transpose_kernel(const float* __restrict__ in,
                                                        unsigned short* __restrict__ out,
                                                        int R, int C) {
    __shared__ float tile[64 * 65];
    const int e = blockIdx.z;
    const float* src = in + (size_t)e * R * C;
    unsigned short* dst = out + (size_t)e * R * C;
    const int c0 = blockIdx.x * 64, r0 = blockIdx.y * 64;
    const int tid = threadIdx.x;
#pragma unroll
    for (int j = 0; j < 4; ++j) {
        int f = j * 256 + tid;
        int row = f >> 4, c4 = f & 15;
        float4 v = *(const float4*)(src + (size_t)(r0 + row) * C + c0 + c4 * 4);
        float* t = &tile[row * 65 + c4 * 4];
        t[0] = v.x; t[1] = v.y; t[2] = v.z; t[3] = v.w;
    }
    __syncthreads();
#pragma unroll
    for (int j = 0; j < 2; ++j) {
        int f = j * 256 + tid;
        int orow = f >> 3, kc = f & 7;
        unsigned short pk[8];
#pragma unroll
        for (int q = 0; q < 8; ++q) pk[q] = f2bf(tile[(kc * 8 + q) * 65 + orow]);
        *(uint4*)(dst + (size_t)(c0 + orow) * R + r0 + kc * 8) = *(uint4*)pk;
    }
}

// ---------------- offsets + aux loss ----------------
__global__ void offsets_aux_kernel(const int* __restrict__ counts, const float* __restrict__ ce_sum,
                                   int* __restrict__ offs, float* __restrict__ aux_out) {
    if (threadIdx.x == 0) {
        int off = 0; float aux = 0.f;
        for (int e = 0; e < 8; ++e) {
            offs[e] = off; off += counts[e];
            aux += ((float)counts[e] / (float)NTOK) * (ce_sum[e] / (float)NTOK);
        }
        aux_out[0] = ALPHA * (float)NEXP * aux;
    }
}

// ---------------- scatter ----------------
__global__ void scatter_kernel(const int* __restrict__ eidx, const int* __restrict__ offs,
                               int* __restrict__ fill, int* __restrict__ toks) {
    int t = blockIdx.x * 256 + threadIdx.x;
    int e = eidx[t];
    int pos = atomicAdd(&fill[e], 1);
    toks[offs[e] + pos] = t;
}

// ======================= GEMM1 =======================
// h = silu(X WuT^T) * (X WvT^T). Round-2 proven body verbatim: 128x128 tile,
// BK=64, 4 waves, single-buffer 2-barrier, launch_bounds(256,2), VGPR 108,
// grid dim3(22, 32, 8) nt-fastest. Measured 101-109 us across rounds 2/5/10.
__global__ __launch_bounds__(256, 2) void gemm1_kernel(
    const unsigned short* __restrict__ WuT, const unsigned short* __restrict__ WvT,
    const unsigned short* __restrict__ xbf,
    const int* __restrict__ toks, const int* __restrict__ counts, const int* __restrict__ offs,
    unsigned short* __restrict__ hbuf) {
    const int e = blockIdx.z;
    const int Ne = counts[e];
    const int mt = blockIdx.y;
    if (mt * 128 >= Ne) return;
    const int nt = blockIdx.x;
    const int slot0 = offs[e] + mt * 128;
    const int rowsV = min(128, Ne - mt * 128);
    const int ncol0 = nt * 128;
    const int colsV = min(128, HID - ncol0);

    __shared__ unsigned short As[128 * 64];
    __shared__ unsigned short Bus[128 * 64];
    __shared__ unsigned short Bvs[128 * 64];

    const int tid = threadIdx.x;

    const unsigned short* aS[4];
    const unsigned short* buS[4];
    const unsigned short* bvS[4];
    unsigned short* aD[4];
    unsigned short* buD[4];
    unsigned short* bvD[4];
#pragma unroll
    for (int i = 0; i < 4; ++i) {
        int c = i * 256 + tid;
        int r = c >> 3, ch = c & 7;
        int srcOff = ((ch ^ (r & 7)) * 8);
        int ar = min(r, rowsV - 1);
        int tok = toks[slot0 + ar];
        aS[i] = xbf + (size_t)tok * D_MODEL + srcOff;
        int bn = ncol0 + min(r, colsV - 1);
        buS[i] = WuT + ((size_t)e * HID + bn) * D_MODEL + srcOff;
        bvS[i] = WvT + ((size_t)e * HID + bn) * D_MODEL + srcOff;
        aD[i]  = As  + c * 8;
        buD[i] = Bus + c * 8;
        bvD[i] = Bvs + c * 8;
    }

    f32x4 accU[4][4], accV[4][4];
#pragma unroll
    for (int m = 0; m < 4; ++m)
#pragma unroll
        for (int n = 0; n < 4; ++n) {
            accU[m][n] = (f32x4){0.f, 0.f, 0.f, 0.f};
            accV[m][n] = (f32x4){0.f, 0.f, 0.f, 0.f};
        }

    const int lane = tid & 63;
    const int w = tid >> 6;
    const int rbase = (w >> 1) * 64;
    const int cbase = (w & 1) * 64;
    const int lrow = lane & 15;
    const int lchunk = lane >> 4;

    for (int ks = 0; ks < 16; ++ks) {
#pragma unroll
        for (int i = 0; i < 4; ++i) gload_lds16(aS[i],  aD[i]);
#pragma unroll
        for (int i = 0; i < 4; ++i) gload_lds16(buS[i], buD[i]);
#pragma unroll
        for (int i = 0; i < 4; ++i) gload_lds16(bvS[i], bvD[i]);
#pragma unroll
        for (int i = 0; i < 4; ++i) { aS[i] += 64; buS[i] += 64; bvS[i] += 64; }
        __syncthreads();

#pragma unroll
        for (int kk = 0; kk < 2; ++kk) {
            const int g = kk * 4 + lchunk;
            bf16x8 af[4], bu[4], bv[4];
#pragma unroll
            for (int m = 0; m < 4; ++m) {
                int r = rbase + m * 16 + lrow;
                af[m] = ldsFrag(&As[r * 64 + ((g ^ (r & 7)) * 8)]);
            }
#pragma unroll
            for (int n = 0; n < 4; ++n) {
                int rn = cbase + n * 16 + lrow;
                int off = rn * 64 + ((g ^ (rn & 7)) * 8);
                bu[n] = ldsFrag(&Bus[off]);
                bv[n] = ldsFrag(&Bvs[off]);
            }
#pragma unroll
            for (int m = 0; m < 4; ++m)
#pragma unroll
                for (int n = 0; n < 4; ++n) {
                    accU[m][n] = __builtin_amdgcn_mfma_f32_16x16x32_bf16(af[m], bu[n], accU[m][n], 0, 0, 0);
                    accV[m][n] = __builtin_amdgcn_mfma_f32_16x16x32_bf16(af[m], bv[n], accV[m][n], 0, 0, 0);
                }
        }
        __syncthreads();
    }

    // epilogue: h = silu(u) * v (bf16)
#pragma unroll
    for (int m = 0; m < 4; ++m) {
#pragma unroll
        for (int i = 0; i < 4; ++i) {
            int r = rbase + m * 16 + (lane >> 4) * 4 + i;
            if (r >= rowsV) continue;
            size_t rowOff = (size_t)(slot0 + r) * HID + ncol0;
#pragma unroll
            for (int n = 0; n < 4; ++n) {
                int c = cbase + n * 16 + (lane & 15);
                if (c < colsV) {
                    float u = accU[m][n][i];
                    float v = accV[m][n][i];
                    float s = u / (1.f + __expf(-u));
                    hbuf[rowOff + c] = f2bf(s * v);
                }
            }
        }
    }
}

// ======================= GEMM2 =======================
// y[tok] = p * (h WdT^T). 128m x 64n, BK=64, static ping-pong dbuf (48KB LDS).
// XCD-pinned 1D grid: id = e + 8*(mt + 32*nt). (Proven rounds 6-10; untouched.)

#define G2_STAGE(AS, BS)                                                  \
    {                                                                     \
        _Pragma("unroll")                                                 \
        for (int i = 0; i < 4; ++i) { gload_lds16(aS[i], &AS[aOff[i]]); aS[i] += 64; } \
        _Pragma("unroll")                                                 \
        for (int i = 0; i < 2; ++i) { gload_lds16(bS[i], &BS[bOff[i]]); bS[i] += 64; } \
    }

#define G2_COMPUTE(AS, BS)                                                \
    {                                                                     \
        _Pragma("unroll")                                                 \
        for (int kk = 0; kk < 2; ++kk) {                                  \
            const int g = kk * 4 + lchunk;                                \
            bf16x8 af[4], bf[2];                                          \
            _Pragma("unroll")                                             \
            for (int m = 0; m < 4; ++m) {                                 \
                int r = rbase + m * 16 + lrow;                            \
                af[m] = ldsFrag(&AS[r * 64 + ((g ^ (r & 7)) * 8)]);       \
            }                                                             \
            _Pragma("unroll")                                             \
            for (int n = 0; n < 2; ++n) {                                 \
                int rn = cbase + n * 16 + lrow;                           \
                bf[n] = ldsFrag(&BS[rn * 64 + ((g ^ (rn & 7)) * 8)]);     \
            }                                                             \
            __builtin_amdgcn_s_setprio(1);                                \
            _Pragma("unroll")                                             \
            for (int m = 0; m < 4; ++m)                                   \
                _Pragma("unroll")                                         \
                for (int n = 0; n < 2; ++n)                               \
                    acc[m][n] = __builtin_amdgcn_mfma_f32_16x16x32_bf16(af[m], bf[n], acc[m][n], 0, 0, 0); \
            __builtin_amdgcn_s_setprio(0);                                \
        }                                                                 \
    }

__global__ __launch_bounds__(256, 2) void gemm2_kernel(
    const unsigned short* __restrict__ WdT, const unsigned short* __restrict__ hbuf,
    const int* __restrict__ toks, const int* __restrict__ counts, const int* __restrict__ offs,
    const float* __restrict__ gate_p, float* __restrict__ yout) {
    const int id = blockIdx.x;
    const int e  = id & 7;
    const int j  = id >> 3;
    const int mt = j & 31;
    const int nt = j >> 5;          // 0..15
    const int Ne = counts[e];
    if (mt * 128 >= Ne) return;
    const int slot0 = offs[e] + mt * 128;
    const int rowsV = min(128, Ne - mt * 128);
    const int ncol0 = nt * 64;

    __shared__ unsigned short As0[128 * 64];
    __shared__ unsigned short As1[128 * 64];
    __shared__ unsigned short Bs0[64 * 64];
    __shared__ unsigned short Bs1[64 * 64];

    const int tid = threadIdx.x;

    const unsigned short* aS[4];
    int aOff[4];
#pragma unroll
    for (int i = 0; i < 4; ++i) {
        int c = i * 256 + tid;
        int r = c >> 3, ch = c & 7;
        int srcOff = (ch ^ (r & 7)) * 8;
        int ar = min(r, rowsV - 1);
        aS[i] = hbuf + (size_t)(slot0 + ar) * HID + srcOff;
        aOff[i] = c * 8;
    }
    const unsigned short* bS[2];
    int bOff[2];
#pragma unroll
    for (int i = 0; i < 2; ++i) {
        int c = i * 256 + tid;
        int r = c >> 3, ch = c & 7;
        int srcOff = (ch ^ (r & 7)) * 8;
        bS[i] = WdT + ((size_t)e * D_MODEL + ncol0 + r) * HID + srcOff;
        bOff[i] = c * 8;
    }

    f32x4 acc[4][2];
#pragma unroll
    for (int m = 0; m < 4; ++m)
#pragma unroll
        for (int n = 0; n < 2; ++n) acc[m][n] = (f32x4){0.f, 0.f, 0.f, 0.f};

    const int lane = tid & 63;
    const int w = tid >> 6;
    const int rbase = (w >> 1) * 64;
    const int cbase = (w & 1) * 32;
    const int lrow = lane & 15;
    const int lchunk = lane >> 4;

    // prologue: step 0 -> buf0
    G2_STAGE(As0, Bs0);
    __syncthreads();

    // 43 K-steps: 21 ping-pong pairs (steps 0..41) + epilogue step 42 in buf0
#pragma unroll 1
    for (int k2 = 0; k2 < 21; ++k2) {
        G2_STAGE(As1, Bs1);          // step 2k+1
        G2_COMPUTE(As0, Bs0);        // step 2k
        __syncthreads();
        G2_STAGE(As0, Bs0);          // step 2k+2  (<= 42)
        G2_COMPUTE(As1, Bs1);        // step 2k+1
        __syncthreads();
    }
    G2_COMPUTE(As0, Bs0);            // step 42

#pragma unroll
    for (int m = 0; m < 4; ++m) {
#pragma unroll
        for (int i = 0; i < 4; ++i) {
            int r = rbase + m * 16 + (lane >> 4) * 4 + i;
            if (r >= rowsV) continue;
            int tok = toks[slot0 + r];
            float p = gate_p[tok];
            float* yrow = yout + (size_t)tok * D_MODEL + ncol0;
#pragma unroll
            for (int n = 0; n < 2; ++n) {
                int c = cbase + n * 16 + (lane & 15);
                yrow[c] = p * acc[m][n][i];
            }
        }
    }
}

// ---------------- launch ----------------
extern "C" void kernel_launch(void* const* d_in, const int* in_sizes, int n_in,
                              void* d_out, int out_size, void* d_ws, size_t ws_size,
                              hipStream_t stream) {
    const float* x  = (const float*)d_in[0];
    const float* Wg = (const float*)d_in[1];
    const float* bg = (const float*)d_in[2];
    const float* Wu = (const float*)d_in[3];
    const float* Wv = (const float*)d_in[4];
    const float* Wd = (const float*)d_in[5];
    float* yout = (float*)d_out;
    float* aux_out = yout + (size_t)NTOK * D_MODEL;

    char* ws = (char*)d_ws;
    int*   counts = (int*)(ws + 0);
    int*   offs   = (int*)(ws + 32);
    float* ce_sum = (float*)(ws + 64);
    int*   fill   = (int*)(ws + 96);
    int*   eidx   = (int*)(ws + 128);
    float* gate_p = (float*)(ws + 16512);
    int*   toks   = (int*)(ws + 32896);
    unsigned short* xbf  = (unsigned short*)(ws + 65536);      // 8 MB
    unsigned short* hbuf = (unsigned short*)(ws + 8454144);    // 22.5 MB
    unsigned short* WuT  = (unsigned short*)(ws + 30998528);   // 43 MB
    unsigned short* WvT  = (unsigned short*)(ws + 76087296);   // 43 MB
    const size_t WDT_OFF = 121176064;
    const size_t WDT_SZ  = (size_t)NEXP * D_MODEL * HID * 2;   // 43 MB
    const bool sepWdT = ws_size >= WDT_OFF + WDT_SZ;           // proven true (round 7)
    unsigned short* WdT = sepWdT ? (unsigned short*)(ws + WDT_OFF) : WuT;

    const int nTiles = sepWdT ? (TILES_UV + TILES_WD) : TILES_UV;

    (void)hipMemsetAsync(ws, 0, 128, stream);
    prep_kernel<<<nTiles + RTR_BLKS, 256, 0, stream>>>(
        x, Wg, bg, Wu, Wv, Wd, WuT, WvT, WdT,
        eidx, gate_p, counts, ce_sum, xbf, nTiles);
    offsets_aux_kernel<<<1, 64, 0, stream>>>(counts, ce_sum, offs, aux_out);
    scatter_kernel<<<16, 256, 0, stream>>>(eidx, offs, fill, toks);
    gemm1_kernel<<<dim3(22, 32, 8), 256, 0, stream>>>(WuT, WvT, xbf, toks, counts, offs, hbuf);
    if (!sepWdT)
        transpose_kernel<<<dim3(D_MODEL / 64, HID / 64, 8), 256, 0, stream>>>(Wd, WdT, HID, D_MODEL);
    gemm2_kernel<<<8 * 32 * 16, 256, 0, stream>>>(WdT, hbuf, toks, counts, offs, gate_p, yout);
}

// Round 13
// 251.107 us; speedup vs baseline: 1.4206x; 1.0034x over previous
//
#include <hip/hip_runtime.h>

// ---------------- problem constants ----------------
#define D_MODEL 1024
#define HID     2752
#define NEXP    8
#define NTOK    4096
#define ALPHA   0.05f

// prep kernel block counts
#define TILES_UV  (43 * 16 * 16)   // 11008: Wu+Wv transpose tiles
#define TILES_WD  (16 * 43 * 8)    // 5504 : Wd transpose tiles
#define RTR_BLKS  1024             // router role: 4 tokens per 256-thr block

// bf16 transpose tile stride (elements)
#define TS 66

typedef __bf16 bf16_t;
typedef bf16_t bf16x8 __attribute__((ext_vector_type(8)));
typedef float  f32x4  __attribute__((ext_vector_type(4)));
typedef float  vf4    __attribute__((ext_vector_type(4)));

// counted-wait primitives (T3/T4): raw barrier + explicit vmcnt, sched fence per rule #18
#define VM_WAIT8  asm volatile("s_waitcnt vmcnt(8)" ::: "memory")
#define VM_WAIT6  asm volatile("s_waitcnt vmcnt(6)" ::: "memory")
#define VM_WAIT0  asm volatile("s_waitcnt vmcnt(0)" ::: "memory")
#define LGKM0     asm volatile("s_waitcnt lgkmcnt(0)" ::: "memory")
#define SBAR      __builtin_amdgcn_s_barrier()
#define SCHED0    __builtin_amdgcn_sched_barrier(0)

__device__ inline unsigned short f2bf(float f) {
    unsigned int u = __float_as_uint(f);
    u += 0x7fffu + ((u >> 16) & 1u);   // round-to-nearest-even
    return (unsigned short)(u >> 16);
}

__device__ inline bf16x8 ldsFrag(const unsigned short* p) {
    union { uint4 u; bf16x8 b; } t;
    t.u = *(const uint4*)p;
    return t.b;
}

__device__ inline void gload_lds16(const void* g, void* l) {
    __builtin_amdgcn_global_load_lds((const __attribute__((address_space(1))) void*)g,
                                     (__attribute__((address_space(3))) void*)l, 16, 0, 0);
}

// ---------------- prep: weight transposes + router, one dispatch (round-12 proven) ----------------
__global__ __launch_bounds__(256) void prep_kernel(
    const float* __restrict__ x, const float* __restrict__ Wg, const float* __restrict__ bg,
    const float* __restrict__ Wu, const float* __restrict__ Wv, const float* __restrict__ Wd,
    unsigned short* __restrict__ WuT, unsigned short* __restrict__ WvT,
    unsigned short* __restrict__ WdT,
    int* __restrict__ eidx, float* __restrict__ gate_p,
    int* __restrict__ counts, float* __restrict__ ce_sum,
    unsigned short* __restrict__ xbf, int nTiles) {

    __shared__ __align__(16) unsigned short tile[64 * TS];   // 8448 B
    const int id = blockIdx.x;
    const int tid = threadIdx.x;

    if (id < nTiles) {
        // ---- transpose role: [R][C] f32 -> [C][R] bf16, 64x64 tile ----
        const int z  = id / 688;
        const int rm = id - z * 688;
        const int bx = rm % 43;
        const int by = rm / 43;
        const float* src;
        unsigned short* dst;
        int R, C, r0, c0;
        if (z < 16) {
            const int e = z & 7;
            src = ((z < 8) ? Wu : Wv) + (size_t)e * D_MODEL * HID;
            dst = ((z < 8) ? WuT : WvT) + (size_t)e * D_MODEL * HID;
            R = D_MODEL; C = HID;
            r0 = by * 64; c0 = bx * 64;
        } else {
            const int e = z - 16;
            src = Wd + (size_t)e * HID * D_MODEL;
            dst = WdT + (size_t)e * HID * D_MODEL;
            R = HID; C = D_MODEL;
            r0 = bx * 64; c0 = by * 64;
        }
#pragma unroll
        for (int j = 0; j < 4; ++j) {
            int f = j * 256 + tid;
            int row = f >> 4, c4 = (f & 15) * 4;
            vf4 v = __builtin_nontemporal_load(
                (const vf4*)(src + (size_t)(r0 + row) * C + c0 + c4));
            unsigned int p0 = (unsigned)f2bf(v.x) | ((unsigned)f2bf(v.y) << 16);
            unsigned int p1 = (unsigned)f2bf(v.z) | ((unsigned)f2bf(v.w) << 16);
            unsigned int* tp = (unsigned int*)&tile[row * TS + c4];
            tp[0] = p0; tp[1] = p1;
        }
        __syncthreads();
#pragma unroll
        for (int j = 0; j < 2; ++j) {
            int f = j * 256 + tid;
            int oc = f >> 3, kc = f & 7;
            unsigned int w[4];
#pragma unroll
            for (int q = 0; q < 4; ++q) {
                unsigned int lo = tile[(kc * 8 + 2 * q)     * TS + oc];
                unsigned int hi = tile[(kc * 8 + 2 * q + 1) * TS + oc];
                w[q] = lo | (hi << 16);
            }
            uint4 out; out.x = w[0]; out.y = w[1]; out.z = w[2]; out.w = w[3];
            *(uint4*)(dst + (size_t)(c0 + oc) * R + r0 + kc * 8) = out;
        }
        return;
    }

    // ---- router role ----
    float* ceS = (float*)tile;
    int*   cntS = (int*)tile + 8;
    if (tid < 8) { ceS[tid] = 0.f; cntS[tid] = 0; }
    __syncthreads();

    const int rid = id - nTiles;
    const int wid = tid >> 6, lane = tid & 63;
    const int t = rid * 4 + wid;
    const float* xr = x + (size_t)t * D_MODEL;
    unsigned short* xbr = xbf + (size_t)t * D_MODEL;

    float acc[8];
#pragma unroll
    for (int e = 0; e < 8; ++e) acc[e] = 0.f;

#pragma unroll
    for (int c = 0; c < 4; ++c) {
        int i0 = c * 256 + lane * 4;
        float4 xv = *(const float4*)(xr + i0);
        uint2 pk;
        pk.x = (unsigned)f2bf(xv.x) | ((unsigned)f2bf(xv.y) << 16);
        pk.y = (unsigned)f2bf(xv.z) | ((unsigned)f2bf(xv.w) << 16);
        *(uint2*)(xbr + i0) = pk;
#pragma unroll
        for (int j = 0; j < 4; ++j) {
            const float* wr = Wg + (size_t)(i0 + j) * 8;
            float4 lo = *(const float4*)(wr);
            float4 hi = *(const float4*)(wr + 4);
            float xs = (&xv.x)[j];
            acc[0] += xs * lo.x; acc[1] += xs * lo.y;
            acc[2] += xs * lo.z; acc[3] += xs * lo.w;
            acc[4] += xs * hi.x; acc[5] += xs * hi.y;
            acc[6] += xs * hi.z; acc[7] += xs * hi.w;
        }
    }
#pragma unroll
    for (int e = 0; e < 8; ++e) {
#pragma unroll
        for (int off = 32; off > 0; off >>= 1)
            acc[e] += __shfl_xor(acc[e], off, 64);
    }

    if (lane == 0) {
        float lg[8];
#pragma unroll
        for (int e = 0; e < 8; ++e) lg[e] = acc[e] + bg[e];
        float mx = lg[0]; int am = 0;
#pragma unroll
        for (int e = 1; e < 8; ++e) { if (lg[e] > mx) { mx = lg[e]; am = e; } }
        float ex[8], s = 0.f;
#pragma unroll
        for (int e = 0; e < 8; ++e) { ex[e] = __expf(lg[e] - mx); s += ex[e]; }
        float inv = 1.f / s;
#pragma unroll
        for (int e = 0; e < 8; ++e) atomicAdd(&ceS[e], ex[e] * inv);
        atomicAdd(&cntS[am], 1);
        eidx[t] = am;
        gate_p[t] = ex[am] * inv;
    }
    __syncthreads();
    if (tid < 8) atomicAdd(&ce_sum[tid], ceS[tid]);
    if (tid >= 8 && tid < 16) atomicAdd(&counts[tid - 8], cntS[tid - 8]);
}

// standalone Wd transpose (fallback when WdT must alias WuT; runs after gemm1)
__global__ __launch_bounds__(256) void transpose_kernel(const float* __restrict__ in,
                                                        unsigned short* __restrict__ out,
                                                        int R, int C) {
    __shared__ float tile[64 * 65];
    const int e = blockIdx.z;
    const float* src = in + (size_t)e * R * C;
    unsigned short* dst = out + (size_t)e * R * C;
    const int c0 = blockIdx.x * 64, r0 = blockIdx.y * 64;
    const int tid = threadIdx.x;
#pragma unroll
    for (int j = 0; j < 4; ++j) {
        int f = j * 256 + tid;
        int row = f >> 4, c4 = f & 15;
        float4 v = *(const float4*)(src + (size_t)(r0 + row) * C + c0 + c4 * 4);
        float* t = &tile[row * 65 + c4 * 4];
        t[0] = v.x; t[1] = v.y; t[2] = v.z; t[3] = v.w;
    }
    __syncthreads();
#pragma unroll
    for (int j = 0; j < 2; ++j) {
        int f = j * 256 + tid;
        int orow = f >> 3, kc = f & 7;
        unsigned short pk[8];
#pragma unroll
        for (int q = 0; q < 8; ++q) pk[q] = f2bf(tile[(kc * 8 + q) * 65 + orow]);
        *(uint4*)(dst + (size_t)(c0 + orow) * R + r0 + kc * 8) = *(uint4*)pk;
    }
}

// ---------------- scatter (+ folded offsets/aux) ----------------
__global__ void scatter_kernel(const int* __restrict__ eidx, const int* __restrict__ counts,
                               const float* __restrict__ ce_sum,
                               int* __restrict__ offs, float* __restrict__ aux_out,
                               int* __restrict__ fill, int* __restrict__ toks) {
    __shared__ int offS[8];
    const int tid = threadIdx.x;
    if (tid == 0) {
        int off = 0; float aux = 0.f;
#pragma unroll
        for (int e = 0; e < 8; ++e) {
            offS[e] = off;
            if (blockIdx.x == 0) offs[e] = off;
            off += counts[e];
            aux += ((float)counts[e] / (float)NTOK) * (ce_sum[e] / (float)NTOK);
        }
        if (blockIdx.x == 0) aux_out[0] = ALPHA * (float)NEXP * aux;
    }
    __syncthreads();
    int t = blockIdx.x * 256 + tid;
    int e = eidx[t];
    int pos = atomicAdd(&fill[e], 1);
    toks[offS[e] + pos] = t;
}

// ======================= GEMM1 =======================
// h = silu(X WuT^T) * (X WvT^T). 128m x 64n, BK=64, 4 waves (64x32 each),
// static ping-pong dbuf (64KB, 2 blocks/CU), T4 counted vmcnt(8) — never drain
// the just-issued stage; grid dim3(43,32,8). Round-6 skeleton (passed, 96 VGPR).

#define G1_STAGE(AS, BUS, BVS)                                            \
    {                                                                     \
        _Pragma("unroll")                                                 \
        for (int i = 0; i < 4; ++i) { gload_lds16(aS[i], &AS[aOff[i]]); aS[i] += 64; } \
        _Pragma("unroll")                                                 \
        for (int i = 0; i < 2; ++i) {                                     \
            gload_lds16(buS[i], &BUS[bOff[i]]); buS[i] += 64;             \
            gload_lds16(bvS[i], &BVS[bOff[i]]); bvS[i] += 64;             \
        }                                                                 \
    }

#define G1_COMPUTE(AS, BUS, BVS)                                          \
    {                                                                     \
        _Pragma("unroll")                                                 \
        for (int kk = 0; kk < 2; ++kk) {                                  \
            const int g = kk * 4 + lchunk;                                \
            bf16x8 af[4], bu[2], bv[2];                                   \
            _Pragma("unroll")                                             \
            for (int m = 0; m < 4; ++m) {                                 \
                int r = rbase + m * 16 + lrow;                            \
                af[m] = ldsFrag(&AS[r * 64 + ((g ^ (r & 7)) * 8)]);       \
            }                                                             \
            _Pragma("unroll")                                             \
            for (int n = 0; n < 2; ++n) {                                 \
                int rn = cbase + n * 16 + lrow;                           \
                int off = rn * 64 + ((g ^ (rn & 7)) * 8);                 \
                bu[n] = ldsFrag(&BUS[off]);                               \
                bv[n] = ldsFrag(&BVS[off]);                               \
            }                                                             \
            __builtin_amdgcn_s_setprio(1);                                \
            _Pragma("unroll")                                             \
            for (int m = 0; m < 4; ++m)                                   \
                _Pragma("unroll")                                         \
                for (int n = 0; n < 2; ++n) {                             \
                    accU[m][n] = __builtin_amdgcn_mfma_f32_16x16x32_bf16(af[m], bu[n], accU[m][n], 0, 0, 0); \
                    accV[m][n] = __builtin_amdgcn_mfma_f32_16x16x32_bf16(af[m], bv[n], accV[m][n], 0, 0, 0); \
                }                                                         \
            __builtin_amdgcn_s_setprio(0);                                \
        }                                                                 \
    }

__global__ __launch_bounds__(256, 2) void gemm1_kernel(
    const unsigned short* __restrict__ WuT, const unsigned short* __restrict__ WvT,
    const unsigned short* __restrict__ xbf,
    const int* __restrict__ toks, const int* __restrict__ counts, const int* __restrict__ offs,
    unsigned short* __restrict__ hbuf) {
    const int e  = blockIdx.z;
    const int mt = blockIdx.y;
    const int nt = blockIdx.x;           // 0..42
    const int Ne = counts[e];
    if (mt * 128 >= Ne) return;
    const int slot0 = offs[e] + mt * 128;
    const int rowsV = min(128, Ne - mt * 128);
    const int ncol0 = nt * 64;

    __shared__ unsigned short As0[128 * 64];
    __shared__ unsigned short As1[128 * 64];
    __shared__ unsigned short Bus0[64 * 64];
    __shared__ unsigned short Bus1[64 * 64];
    __shared__ unsigned short Bvs0[64 * 64];
    __shared__ unsigned short Bvs1[64 * 64];

    const int tid = threadIdx.x;

    const unsigned short* aS[4];
    int aOff[4];
#pragma unroll
    for (int i = 0; i < 4; ++i) {
        int c = i * 256 + tid;
        int r = c >> 3, ch = c & 7;
        int srcOff = (ch ^ (r & 7)) * 8;
        int ar = min(r, rowsV - 1);
        int tok = toks[slot0 + ar];
        aS[i] = xbf + (size_t)tok * D_MODEL + srcOff;
        aOff[i] = c * 8;
    }
    const unsigned short *buS[2], *bvS[2];
    int bOff[2];
#pragma unroll
    for (int i = 0; i < 2; ++i) {
        int c = i * 256 + tid;
        int r = c >> 3, ch = c & 7;
        int srcOff = (ch ^ (r & 7)) * 8;
        int bn = ncol0 + r;
        buS[i] = WuT + ((size_t)e * HID + bn) * D_MODEL + srcOff;
        bvS[i] = WvT + ((size_t)e * HID + bn) * D_MODEL + srcOff;
        bOff[i] = c * 8;
    }

    f32x4 accU[4][2], accV[4][2];
#pragma unroll
    for (int m = 0; m < 4; ++m)
#pragma unroll
        for (int n = 0; n < 2; ++n) {
            accU[m][n] = (f32x4){0.f, 0.f, 0.f, 0.f};
            accV[m][n] = (f32x4){0.f, 0.f, 0.f, 0.f};
        }

    const int lane = tid & 63;
    const int w = tid >> 6;
    const int rbase = (w >> 1) * 64;
    const int cbase = (w & 1) * 32;
    const int lrow = lane & 15;
    const int lchunk = lane >> 4;

    // prologue: k=0 -> buf0 (8 VMEM outstanding)
    G1_STAGE(As0, Bus0, Bvs0);

#pragma unroll 1
    for (int k2 = 0; k2 < 7; ++k2) {
        G1_STAGE(As1, Bus1, Bvs1);               // k = 2k2+1
        VM_WAIT8; SBAR; SCHED0;                  // prior step's loads landed everywhere
        G1_COMPUTE(As0, Bus0, Bvs0);             // k = 2k2
        SCHED0; LGKM0; SBAR;                     // all waves done reading buf0
        G1_STAGE(As0, Bus0, Bvs0);               // k = 2k2+2
        VM_WAIT8; SBAR; SCHED0;
        G1_COMPUTE(As1, Bus1, Bvs1);             // k = 2k2+1
        SCHED0; LGKM0; SBAR;
    }
    G1_STAGE(As1, Bus1, Bvs1);                   // k = 15
    VM_WAIT8; SBAR; SCHED0;
    G1_COMPUTE(As0, Bus0, Bvs0);                 // k = 14
    SCHED0; LGKM0; SBAR;
    VM_WAIT0; SBAR; SCHED0;
    G1_COMPUTE(As1, Bus1, Bvs1);                 // k = 15

    // epilogue: h = silu(u) * v (bf16); HID = 43*64 so no column guard
#pragma unroll
    for (int m = 0; m < 4; ++m) {
#pragma unroll
        for (int i = 0; i < 4; ++i) {
            int r = rbase + m * 16 + (lane >> 4) * 4 + i;
            if (r >= rowsV) continue;
            size_t rowOff = (size_t)(slot0 + r) * HID + ncol0;
#pragma unroll
            for (int n = 0; n < 2; ++n) {
                int c = cbase + n * 16 + (lane & 15);
                float u = accU[m][n][i];
                float v = accV[m][n][i];
                float s = u / (1.f + __expf(-u));
                hbuf[rowOff + c] = f2bf(s * v);
            }
        }
    }
}

// ======================= GEMM2 =======================
// y[tok] = p * (h WdT^T). 128m x 64n, BK=64, static ping-pong dbuf (48KB),
// T4 counted vmcnt(6). XCD-pinned 1D grid: id = e + 8*(mt + 32*nt).

#define G2_STAGE(AS, BS)                                                  \
    {                                                                     \
        _Pragma("unroll")                                                 \
        for (int i = 0; i < 4; ++i) { gload_lds16(aS[i], &AS[aOff[i]]); aS[i] += 64; } \
        _Pragma("unroll")                                                 \
        for (int i = 0; i < 2; ++i) { gload_lds16(bS[i], &BS[bOff[i]]); bS[i] += 64; } \
    }

#define G2_COMPUTE(AS, BS)                                                \
    {                                                                     \
        _Pragma("unroll")                                                 \
        for (int kk = 0; kk < 2; ++kk) {                                  \
            const int g = kk * 4 + lchunk;                                \
            bf16x8 af[4], bf[2];                                          \
            _Pragma("unroll")                                             \
            for (int m = 0; m < 4; ++m) {                                 \
                int r = rbase + m * 16 + lrow;                            \
                af[m] = ldsFrag(&AS[r * 64 + ((g ^ (r & 7)) * 8)]);       \
            }                                                             \
            _Pragma("unroll")                                             \
            for (int n = 0; n < 2; ++n) {                                 \
                int rn = cbase + n * 16 + lrow;                           \
                bf[n] = ldsFrag(&BS[rn * 64 + ((g ^ (rn & 7)) * 8)]);     \
            }                                                             \
            __builtin_amdgcn_s_setprio(1);                                \
            _Pragma("unroll")                                             \
            for (int m = 0; m < 4; ++m)                                   \
                _Pragma("unroll")                                         \
                for (int n = 0; n < 2; ++n)                               \
                    acc[m][n] = __builtin_amdgcn_mfma_f32_16x16x32_bf16(af[m], bf[n], acc[m][n], 0, 0, 0); \
            __builtin_amdgcn_s_setprio(0);                                \
        }                                                                 \
    }

__global__ __launch_bounds__(256, 2) void gemm2_kernel(
    const unsigned short* __restrict__ WdT, const unsigned short* __restrict__ hbuf,
    const int* __restrict__ toks, const int* __restrict__ counts, const int* __restrict__ offs,
    const float* __restrict__ gate_p, float* __restrict__ yout) {
    const int id = blockIdx.x;
    const int e  = id & 7;
    const int j  = id >> 3;
    const int mt = j & 31;
    const int nt = j >> 5;          // 0..15
    const int Ne = counts[e];
    if (mt * 128 >= Ne) return;
    const int slot0 = offs[e] + mt * 128;
    const int rowsV = min(128, Ne - mt * 128);
    const int ncol0 = nt * 64;

    __shared__ unsigned short As0[128 * 64];
    __shared__ unsigned short As1[128 * 64];
    __shared__ unsigned short Bs0[64 * 64];
    __shared__ unsigned short Bs1[64 * 64];

    const int tid = threadIdx.x;

    const unsigned short* aS[4];
    int aOff[4];
#pragma unroll
    for (int i = 0; i < 4; ++i) {
        int c = i * 256 + tid;
        int r = c >> 3, ch = c & 7;
        int srcOff = (ch ^ (r & 7)) * 8;
        int ar = min(r, rowsV - 1);
        aS[i] = hbuf + (size_t)(slot0 + ar) * HID + srcOff;
        aOff[i] = c * 8;
    }
    const unsigned short* bS[2];
    int bOff[2];
#pragma unroll
    for (int i = 0; i < 2; ++i) {
        int c = i * 256 + tid;
        int r = c >> 3, ch = c & 7;
        int srcOff = (ch ^ (r & 7)) * 8;
        bS[i] = WdT + ((size_t)e * D_MODEL + ncol0 + r) * HID + srcOff;
        bOff[i] = c * 8;
    }

    f32x4 acc[4][2];
#pragma unroll
    for (int m = 0; m < 4; ++m)
#pragma unroll
        for (int n = 0; n < 2; ++n) acc[m][n] = (f32x4){0.f, 0.f, 0.f, 0.f};

    const int lane = tid & 63;
    const int w = tid >> 6;
    const int rbase = (w >> 1) * 64;
    const int cbase = (w & 1) * 32;
    const int lrow = lane & 15;
    const int lchunk = lane >> 4;

    // prologue: k=0 -> buf0
    G2_STAGE(As0, Bs0);

    // 43 K-steps: 21 counted-wait pairs (k=0..41) + final step 42
#pragma unroll 1
    for (int k2 = 0; k2 < 21; ++k2) {
        G2_STAGE(As1, Bs1);                      // k = 2k2+1
        VM_WAIT6; SBAR; SCHED0;
        G2_COMPUTE(As0, Bs0);                    // k = 2k2
        SCHED0; LGKM0; SBAR;
        G2_STAGE(As0, Bs0);                      // k = 2k2+2 (<= 42)
        VM_WAIT6; SBAR; SCHED0;
        G2_COMPUTE(As1, Bs1);                    // k = 2k2+1
        SCHED0; LGKM0; SBAR;
    }
    VM_WAIT0; SBAR; SCHED0;
    G2_COMPUTE(As0, Bs0);                        // k = 42

#pragma unroll
    for (int m = 0; m < 4; ++m) {
#pragma unroll
        for (int i = 0; i < 4; ++i) {
            int r = rbase + m * 16 + (lane >> 4) * 4 + i;
            if (r >= rowsV) continue;
            int tok = toks[slot0 + r];
            float p = gate_p[tok];
            float* yrow = yout + (size_t)tok * D_MODEL + ncol0;
#pragma unroll
            for (int n = 0; n < 2; ++n) {
                int c = cbase + n * 16 + (lane & 15);
                yrow[c] = p * acc[m][n][i];
            }
        }
    }
}

// ---------------- launch ----------------
extern "C" void kernel_launch(void* const* d_in, const int* in_sizes, int n_in,
                              void* d_out, int out_size, void* d_ws, size_t ws_size,
                              hipStream_t stream) {
    const float* x  = (const float*)d_in[0];
    const float* Wg = (const float*)d_in[1];
    const float* bg = (const float*)d_in[2];
    const float* Wu = (const float*)d_in[3];
    const float* Wv = (const float*)d_in[4];
    const float* Wd = (const float*)d_in[5];
    float* yout = (float*)d_out;
    float* aux_out = yout + (size_t)NTOK * D_MODEL;

    char* ws = (char*)d_ws;
    int*   counts = (int*)(ws + 0);
    int*   offs   = (int*)(ws + 32);
    float* ce_sum = (float*)(ws + 64);
    int*   fill   = (int*)(ws + 96);
    int*   eidx   = (int*)(ws + 128);
    float* gate_p = (float*)(ws + 16512);
    int*   toks   = (int*)(ws + 32896);
    unsigned short* xbf  = (unsigned short*)(ws + 65536);      // 8 MB
    unsigned short* hbuf = (unsigned short*)(ws + 8454144);    // 22.5 MB
    unsigned short* WuT  = (unsigned short*)(ws + 30998528);   // 43 MB
    unsigned short* WvT  = (unsigned short*)(ws + 76087296);   // 43 MB
    const size_t WDT_OFF = 121176064;
    const size_t WDT_SZ  = (size_t)NEXP * D_MODEL * HID * 2;   // 43 MB
    const bool sepWdT = ws_size >= WDT_OFF + WDT_SZ;           // proven true (round 7)
    unsigned short* WdT = sepWdT ? (unsigned short*)(ws + WDT_OFF) : WuT;

    const int nTiles = sepWdT ? (TILES_UV + TILES_WD) : TILES_UV;

    (void)hipMemsetAsync(ws, 0, 128, stream);
    prep_kernel<<<nTiles + RTR_BLKS, 256, 0, stream>>>(
        x, Wg, bg, Wu, Wv, Wd, WuT, WvT, WdT,
        eidx, gate_p, counts, ce_sum, xbf, nTiles);
    scatter_kernel<<<16, 256, 0, stream>>>(eidx, counts, ce_sum, offs, aux_out, fill, toks);
    gemm1_kernel<<<dim3(43, 32, 8), 256, 0, stream>>>(WuT, WvT, xbf, toks, counts, offs, hbuf);
    if (!sepWdT)
        transpose_kernel<<<dim3(D_MODEL / 64, HID / 64, 8), 256, 0, stream>>>(Wd, WdT, HID, D_MODEL);
    gemm2_kernel<<<8 * 32 * 16, 256, 0, stream>>>(WdT, hbuf, toks, counts, offs, gate_p, yout);
}